// Round 1
// 382.461 us; speedup vs baseline: 1.0661x; 1.0661x over previous
//
#include <hip/hip_runtime.h>
#include <hip/hip_bf16.h>

// Problem dims (compile-time constants, match reference)
constexpr int B  = 8;
constexpr int A  = 6;     // agents: both query count and key count
constexpr int QS = 32;
constexpr int KS = 1024;
constexpr int C  = 256;
constexpr int H  = 64;
constexpr int W_ = 64;
constexpr long CHW  = (long)C * H * W_;        // 1,048,576 floats per (b,k) plane
constexpr long CHW4 = CHW / 4;                  // 262,144 float4s
constexpr int  BLOCKS_PER_B = (int)(CHW4 / 256); // 1024 blocks of 256 threads per batch

typedef float f32x4 __attribute__((ext_vector_type(4)));

// ---------------------------------------------------------------------------
// Kernel 1: tiny attention head. One block per batch b (8 blocks total).
//   query[q][d] = sum_s qu[b,q,s] * W[d,s] + bias[d]          (6 x 1024)
//   attn[k][q]  = sum_d k[b,k,d] * query[q][d]                (6 x 6)
//   attn_sm     = softmax over k (axis=1)                     (6 x 6)
// v2: W is staged through LDS with fully-coalesced float4 loads (the old
// version had every lane reading a 128B-strided W row straight from global —
// uncoalesced and serialized at 1 wave/SIMD occupancy). Padded LDS row (+1)
// gives 2-way bank aliasing on the compute reads, which is free on CDNA4.
// ---------------------------------------------------------------------------
__global__ __launch_bounds__(256) void attn_kernel(
    const float* __restrict__ qu,    // [B,A,QS]
    const float* __restrict__ kmat,  // [B,A,KS]
    const float* __restrict__ Wm,    // [KS,QS]
    const float* __restrict__ bias,  // [KS]
    float* __restrict__ attn_out)    // [B,A,A]  (b,k,q)
{
    __shared__ float s_qu[A][QS];
    __shared__ float s_w[256][QS + 1];   // one 256-row chunk of W, +1 pad
    __shared__ float s_query[A][KS];
    __shared__ float s_attn[A][A];       // [k][q]

    const int b   = blockIdx.x;
    const int tid = threadIdx.x;

    // stage qu[b] (768 floats)
    for (int i = tid; i < A * QS; i += 256) s_qu[i / QS][i % QS] = qu[b * A * QS + i];
    __syncthreads();

    // query projection in 4 chunks of 256 d's; each thread owns one d per chunk
    for (int chunk = 0; chunk < KS / 256; ++chunk) {
        // coalesced stage of 256 W rows (8192 floats = 2048 float4)
        const f32x4* wsrc = reinterpret_cast<const f32x4*>(Wm + (long)chunk * 256 * QS);
        #pragma unroll
        for (int j = 0; j < 8; ++j) {
            const int f4  = j * 256 + tid;      // 0..2047
            const f32x4 w4 = wsrc[f4];
            const int row = f4 >> 3;            // 8 float4 per 32-float row
            const int col = (f4 & 7) * 4;
            s_w[row][col + 0] = w4.x;
            s_w[row][col + 1] = w4.y;
            s_w[row][col + 2] = w4.z;
            s_w[row][col + 3] = w4.w;
        }
        __syncthreads();

        const int d  = chunk * 256 + tid;
        const float bd = bias[d];               // coalesced
        float acc[A];
        #pragma unroll
        for (int q = 0; q < A; ++q) acc[q] = bd;
        #pragma unroll
        for (int s = 0; s < QS; ++s) {
            const float w = s_w[tid][s];        // bank (lane+s)%32 -> 2-way, free
            #pragma unroll
            for (int q = 0; q < A; ++q) acc[q] += w * s_qu[q][s];
        }
        #pragma unroll
        for (int q = 0; q < A; ++q) s_query[q][d] = acc[q];
        __syncthreads();                        // protects s_w reuse + final s_query
    }

    // 36 scores; 4 waves, 9 pairs each; 1024-dot split across 64 lanes
    const int wave = tid >> 6;
    const int lane = tid & 63;
    for (int p = wave; p < A * A; p += 4) {
        const int kk = p / A;
        const int q  = p % A;
        const float* krow = kmat + ((long)b * A + kk) * KS;
        float partial = 0.f;
        for (int d = lane; d < KS; d += 64) partial += krow[d] * s_query[q][d];
        #pragma unroll
        for (int off = 32; off > 0; off >>= 1)
            partial += __shfl_down(partial, off, 64);
        if (lane == 0) s_attn[kk][q] = partial;
    }
    __syncthreads();

    // softmax over k for each q (6 lanes do the 6 columns)
    if (tid < A) {
        const int q = tid;
        float m = s_attn[0][q];
        #pragma unroll
        for (int kk = 1; kk < A; ++kk) m = fmaxf(m, s_attn[kk][q]);
        float e[A];
        float sum = 0.f;
        #pragma unroll
        for (int kk = 0; kk < A; ++kk) { e[kk] = expf(s_attn[kk][q] - m); sum += e[kk]; }
        const float inv = 1.f / sum;
        #pragma unroll
        for (int kk = 0; kk < A; ++kk)
            attn_out[b * A * A + kk * A + q] = e[kk] * inv;
    }
}

// ---------------------------------------------------------------------------
// Kernel 2: weighted combine. out[b,q,chw] = sum_k attn[b,k,q] * v[b,k,chw].
// Each thread: 6 float4 loads (one per k-plane), 6 float4 stores (one per
// q-plane). Reads v exactly once, writes out exactly once -> HBM-minimal.
// v2: - nontemporal loads/stores: v+out streams total 403 MB > 256 MB L3 and
//       have zero reuse; skip L2/L3 allocation entirely.
//     - attn (36 floats) read via wave-uniform global loads (scalar-load
//       broadcast) instead of LDS + __syncthreads: no barrier, no LDS.
// ---------------------------------------------------------------------------
__global__ __launch_bounds__(256) void combine_kernel(
    const float* __restrict__ v,     // [B,A,C,H,W]
    const float* __restrict__ attn,  // [B,A,A]  (b,k,q)
    float* __restrict__ out)         // [B,A,C,H,W] (b,q,...)
{
    const int b   = blockIdx.x >> 10;         // / BLOCKS_PER_B
    const int blk = blockIdx.x & (BLOCKS_PER_B - 1);

    // wave-uniform address -> compiler emits scalar (broadcast) loads
    float a[A * A];
    const float* __restrict__ ab = attn + b * A * A;
    #pragma unroll
    for (int i = 0; i < A * A; ++i) a[i] = ab[i];

    const long i4   = (long)blk * 256 + threadIdx.x;   // float4 index in plane
    const long base = (long)b * A * CHW4 + i4;
    const f32x4* __restrict__ vb = reinterpret_cast<const f32x4*>(v)   + base;
    f32x4*       __restrict__ ob = reinterpret_cast<f32x4*>(out)       + base;

    f32x4 vv[A];
    #pragma unroll
    for (int kk = 0; kk < A; ++kk)
        vv[kk] = __builtin_nontemporal_load(vb + (long)kk * CHW4);

    #pragma unroll
    for (int q = 0; q < A; ++q) {
        f32x4 acc = (f32x4){0.f, 0.f, 0.f, 0.f};
        #pragma unroll
        for (int kk = 0; kk < A; ++kk)
            acc += a[kk * A + q] * vv[kk];
        __builtin_nontemporal_store(acc, ob + (long)q * CHW4);
    }
}

extern "C" void kernel_launch(void* const* d_in, const int* in_sizes, int n_in,
                              void* d_out, int out_size, void* d_ws, size_t ws_size,
                              hipStream_t stream) {
    const float* qu   = (const float*)d_in[0];
    const float* kmat = (const float*)d_in[1];
    const float* v    = (const float*)d_in[2];
    const float* Wm   = (const float*)d_in[3];
    const float* bias = (const float*)d_in[4];

    float* out      = (float*)d_out;
    float* attn_out = out + (long)B * A * CHW;   // tuple output #1 lives after out

    attn_kernel<<<B, 256, 0, stream>>>(qu, kmat, Wm, bias, attn_out);
    combine_kernel<<<B * BLOCKS_PER_B, 256, 0, stream>>>(v, attn_out, out);
}